// Round 1
// baseline (346.183 us; speedup 1.0000x reference)
//
#include <hip/hip_runtime.h>
#include <hip/hip_bf16.h>

#define N_NODES    100000
#define N_EDGES    1600000
#define NODE_DIM   128
#define EDGE_DIM   32
#define GLOBAL_DIM 64
#define HIDDEN_DIM 256
#define N_GRAPHS   512
#define IN_DIM     224   // 128 + 32 + 64

#define NSLOT      32    // edge accumulator copies (contention spreading)
#define NODE_BLKS  1024
#define NODE_WAVES (NODE_BLKS * 4)
#define EDGE_BLKS  512

// ---------------- workspace layout (floats) ----------------
// node_sum : N_GRAPHS*NODE_DIM           = 65536
// node_cnt : N_GRAPHS                    = 512
// eslot    : NSLOT*N_GRAPHS*EDGE_DIM     = 524288
// ecnt     : NSLOT*N_GRAPHS              = 16384
// feat     : N_GRAPHS*IN_DIM             = 114688
#define WS_NODE_SUM 0
#define WS_NODE_CNT (WS_NODE_SUM + N_GRAPHS * NODE_DIM)
#define WS_ESLOT    (WS_NODE_CNT + N_GRAPHS)
#define WS_ECNT     (WS_ESLOT + NSLOT * N_GRAPHS * EDGE_DIM)
#define WS_FEAT     (WS_ECNT + NSLOT * N_GRAPHS)
#define WS_ZERO_FLOATS WS_FEAT   // everything before feat must be zeroed

// ---------------- node scatter-sum (batch is sorted: run-length in regs) ----
__global__ __launch_bounds__(256) void node_scatter(const float* __restrict__ x,
                                                    const int* __restrict__ batch,
                                                    float* __restrict__ nsum,
                                                    float* __restrict__ ncnt) {
    int w = (blockIdx.x * blockDim.x + threadIdx.x) >> 6;
    int lane = threadIdx.x & 63;
    const int CH = (N_NODES + NODE_WAVES - 1) / NODE_WAVES;  // 25
    int s = w * CH;
    int e = min(s + CH, N_NODES);
    if (s >= e) return;

    float ax = 0.f, ay = 0.f;
    int cur = batch[s];
    int run = 0;
    for (int i = s; i < e; ++i) {
        int b = batch[i];
        if (b != cur) {
            atomicAdd(&nsum[cur * NODE_DIM + lane * 2 + 0], ax);
            atomicAdd(&nsum[cur * NODE_DIM + lane * 2 + 1], ay);
            if (lane == 0) atomicAdd(&ncnt[cur], (float)run);
            ax = ay = 0.f; run = 0; cur = b;
        }
        const float2 v = *reinterpret_cast<const float2*>(x + (size_t)i * NODE_DIM + lane * 2);
        ax += v.x; ay += v.y; ++run;
    }
    atomicAdd(&nsum[cur * NODE_DIM + lane * 2 + 0], ax);
    atomicAdd(&nsum[cur * NODE_DIM + lane * 2 + 1], ay);
    if (lane == 0) atomicAdd(&ncnt[cur], (float)run);
}

// ---------------- edge scatter-sum (random segs: LDS histogram) ------------
// LDS: [512 graphs][33] — cols 0..31 = dim sums, col 32 = count.
// Stride 33 => bank = (seg + col) % 32; random segs spread banks.
__global__ __launch_bounds__(256) void edge_scatter(const float* __restrict__ eattr,
                                                    const int* __restrict__ eidx,   // row 0 of edge_index
                                                    const int* __restrict__ batch,
                                                    float* __restrict__ eslot,
                                                    float* __restrict__ ecnt) {
    __shared__ float ssum[N_GRAPHS * 33];
    for (int i = threadIdx.x; i < N_GRAPHS * 33; i += 256) ssum[i] = 0.f;
    __syncthreads();

    const int CH = (N_EDGES + EDGE_BLKS - 1) / EDGE_BLKS;  // 3125
    const int e0 = blockIdx.x * CH;
    const int e1 = min(e0 + CH, N_EDGES);
    const int p  = threadIdx.x & 7;   // 8 lanes per 32-float edge row

    for (int e = e0 + (threadIdx.x >> 3); e < e1; e += 32) {
        int src = eidx[e];
        int seg = batch[src];
        const float4 v = *reinterpret_cast<const float4*>(eattr + (size_t)e * EDGE_DIM + p * 4);
        float* row = ssum + seg * 33;
        atomicAdd(row + p * 4 + 0, v.x);
        atomicAdd(row + p * 4 + 1, v.y);
        atomicAdd(row + p * 4 + 2, v.z);
        atomicAdd(row + p * 4 + 3, v.w);
        if (p == 0) atomicAdd(row + 32, 1.f);
    }
    __syncthreads();

    const int slot = blockIdx.x & (NSLOT - 1);
    float* gs = eslot + (size_t)slot * N_GRAPHS * EDGE_DIM;
    for (int i = threadIdx.x; i < N_GRAPHS * EDGE_DIM; i += 256) {
        float v = ssum[(i >> 5) * 33 + (i & 31)];
        if (v != 0.f) atomicAdd(gs + i, v);
    }
    float* gc = ecnt + slot * N_GRAPHS;
    for (int i = threadIdx.x; i < N_GRAPHS; i += 256) {
        float v = ssum[i * 33 + 32];
        if (v != 0.f) atomicAdd(gc + i, v);
    }
}

// ---------------- finalize: means + concat [node_mean | edge_mean | u] -----
__global__ __launch_bounds__(256) void finalize_feat(const float* __restrict__ nsum,
                                                     const float* __restrict__ ncnt,
                                                     const float* __restrict__ eslot,
                                                     const float* __restrict__ ecnt,
                                                     const float* __restrict__ u,
                                                     float* __restrict__ feat) {
    int g = blockIdx.x;
    int t = threadIdx.x;
    __shared__ float s_nc, s_ec;
    if (t == 0) {
        s_nc = fmaxf(ncnt[g], 1.f);
    } else if (t == 64) {
        float c = 0.f;
        for (int s = 0; s < NSLOT; ++s) c += ecnt[s * N_GRAPHS + g];
        s_ec = fmaxf(c, 1.f);
    }
    __syncthreads();
    if (t < NODE_DIM) {
        feat[g * IN_DIM + t] = nsum[g * NODE_DIM + t] / s_nc;
    } else if (t < NODE_DIM + EDGE_DIM) {
        int d = t - NODE_DIM;
        float s = 0.f;
        for (int sl = 0; sl < NSLOT; ++sl) s += eslot[(size_t)sl * N_GRAPHS * EDGE_DIM + g * EDGE_DIM + d];
        feat[g * IN_DIM + t] = s / s_ec;
    } else if (t < IN_DIM) {
        feat[g * IN_DIM + t] = u[g * GLOBAL_DIM + (t - NODE_DIM - EDGE_DIM)];
    }
}

// ---------------- 3-layer MLP: one block per graph -------------------------
__global__ __launch_bounds__(256) void mlp_kernel(const float* __restrict__ feat,
                                                  const float* __restrict__ W1, const float* __restrict__ b1,
                                                  const float* __restrict__ W2, const float* __restrict__ b2,
                                                  const float* __restrict__ W3, const float* __restrict__ b3,
                                                  float* __restrict__ out) {
    int g = blockIdx.x;
    int j = threadIdx.x;
    __shared__ float h[HIDDEN_DIM];
    __shared__ float h2[HIDDEN_DIM];
    __shared__ float red[256];

    const float* f = feat + g * IN_DIM;
    float acc = b1[j];
#pragma unroll 4
    for (int k = 0; k < IN_DIM; ++k) acc = fmaf(f[k], W1[k * HIDDEN_DIM + j], acc);
    h[j] = fmaxf(acc, 0.f);
    __syncthreads();

    float acc2 = b2[j];
#pragma unroll 4
    for (int k = 0; k < HIDDEN_DIM; ++k) acc2 = fmaf(h[k], W2[k * HIDDEN_DIM + j], acc2);
    h2[j] = fmaxf(acc2, 0.f);
    __syncthreads();

    // last layer: 64 cols, split K across 4 groups then LDS-reduce
    int col = j & 63;
    int q = j >> 6;
    float acc3 = 0.f;
#pragma unroll 4
    for (int k = q * 64; k < q * 64 + 64; ++k) acc3 = fmaf(h2[k], W3[k * GLOBAL_DIM + col], acc3);
    red[j] = acc3;
    __syncthreads();
    if (j < GLOBAL_DIM) {
        out[g * GLOBAL_DIM + j] = red[j] + red[j + 64] + red[j + 128] + red[j + 192] + b3[j];
    }
}

extern "C" void kernel_launch(void* const* d_in, const int* in_sizes, int n_in,
                              void* d_out, int out_size, void* d_ws, size_t ws_size,
                              hipStream_t stream) {
    const float* x         = (const float*)d_in[0];
    const int*   edge_idx  = (const int*)d_in[1];    // [2, E]; row 0 = sources
    const float* edge_attr = (const float*)d_in[2];
    const float* u         = (const float*)d_in[3];
    const int*   batch     = (const int*)d_in[4];
    const float* W1 = (const float*)d_in[5];
    const float* b1 = (const float*)d_in[6];
    const float* W2 = (const float*)d_in[7];
    const float* b2 = (const float*)d_in[8];
    const float* W3 = (const float*)d_in[9];
    const float* b3 = (const float*)d_in[10];
    float* out = (float*)d_out;

    float* ws = (float*)d_ws;
    float* nsum  = ws + WS_NODE_SUM;
    float* ncnt  = ws + WS_NODE_CNT;
    float* eslot = ws + WS_ESLOT;
    float* ecnt  = ws + WS_ECNT;
    float* feat  = ws + WS_FEAT;

    // zero the accumulators (graph replays reuse ws — atomics would accumulate)
    hipMemsetAsync(d_ws, 0, (size_t)WS_ZERO_FLOATS * sizeof(float), stream);

    node_scatter<<<NODE_BLKS, 256, 0, stream>>>(x, batch, nsum, ncnt);
    edge_scatter<<<EDGE_BLKS, 256, 0, stream>>>(edge_attr, edge_idx, batch, eslot, ecnt);
    finalize_feat<<<N_GRAPHS, 256, 0, stream>>>(nsum, ncnt, eslot, ecnt, u, feat);
    mlp_kernel<<<N_GRAPHS, 256, 0, stream>>>(feat, W1, b1, W2, b2, W3, b3, out);
}